// Round 2
// baseline (815.661 us; speedup 1.0000x reference)
//
#include <hip/hip_runtime.h>
#include <hip/hip_bf16.h>

typedef __hip_bfloat16 bf16;
using bf16x8 = __attribute__((ext_vector_type(8))) short;
using f32x4  = __attribute__((ext_vector_type(4))) float;

#define S_LEN 1024
#define CDIM  576
#define NHEAD 8
#define DKH   72
#define BATCH 4
#define MROWS 4096   // B*S
#define FFDIM 2304
#define QKVN  1728   // 3*C (logical)
#define QKVS  1792   // padded to 14*128 for 128x128 GEMM tiles

// async global->LDS, 16B per lane, lane-ordered LDS destination
__device__ __forceinline__ void gload16(const void* g, void* l) {
  __builtin_amdgcn_global_load_lds(
      (const __attribute__((address_space(1))) unsigned int*)g,
      (__attribute__((address_space(3))) unsigned int*)l, 16, 0, 0);
}

// float -> bf16 bits (RNE), pure integer math (type-safe for LDS punning)
__device__ __forceinline__ short f2bf_bits(float x) {
  unsigned int u = __float_as_uint(x);
  u += 0x7fffu + ((u >> 16) & 1u);
  return (short)(u >> 16);
}

// ---------------- weight transpose + fp32->bf16 convert ----------------
// in: per-layer [K,N] fp32 (layer stride in_ls) -> out: [N,K] bf16 (layer stride out_ls)
__global__ __launch_bounds__(256) void transpose_cvt(
    const float* __restrict__ in, bf16* __restrict__ out, int K, int N,
    size_t in_ls, size_t out_ls) {
  __shared__ float tile[32][33];
  const float* inl = in + (size_t)blockIdx.z * in_ls;
  bf16* outl = out + (size_t)blockIdx.z * out_ls;
  int n0 = blockIdx.x * 32, k0 = blockIdx.y * 32;
  int tx = threadIdx.x & 31, ty = threadIdx.x >> 5;   // ty 0..7
#pragma unroll
  for (int i = 0; i < 32; i += 8)
    tile[ty + i][tx] = inl[(size_t)(k0 + ty + i) * N + (n0 + tx)];
  __syncthreads();
#pragma unroll
  for (int i = 0; i < 32; i += 8)
    outl[(size_t)(n0 + ty + i) * K + (k0 + tx)] = __float2bfloat16(tile[tx][ty + i]);
}

// ---------------- xf = right_shift(x) + pos ----------------
__global__ __launch_bounds__(256) void build_xf(
    const float* __restrict__ x, const float* __restrict__ p0,
    const float* __restrict__ p1, const float* __restrict__ p2,
    float* __restrict__ xf) {
  int idx = blockIdx.x * 256 + threadIdx.x;      // one float4 per thread
  int c4 = idx % 144;
  int s  = (idx / 144) & (S_LEN - 1);
  int b  = idx / (144 * S_LEN);
  int c  = c4 * 4;
  int t = s >> 8, hh = (s >> 4) & 15, w = s & 15;
  float4 pv;
  if (c < 192)       pv = *(const float4*)&p0[t  * 192 + c];
  else if (c < 384)  pv = *(const float4*)&p1[hh * 192 + c - 192];
  else               pv = *(const float4*)&p2[w  * 192 + c - 384];
  float4 xv = make_float4(0.f, 0.f, 0.f, 0.f);
  if (s > 0) xv = *(const float4*)&x[((size_t)b * S_LEN + s - 1) * CDIM + c];
  float4 r = make_float4(xv.x + pv.x, xv.y + pv.y, xv.z + pv.z, xv.w + pv.w);
  *(float4*)&xf[((size_t)b * S_LEN + s) * CDIM + c] = r;
}

// ---------------- LayerNorm (eps added to rsqrt, per reference) ----------------
__global__ __launch_bounds__(256) void ln_kernel(
    const float* __restrict__ x, const float* __restrict__ g,
    const float* __restrict__ b, bf16* __restrict__ out) {
  int row  = blockIdx.x * 4 + (threadIdx.x >> 6);
  int lane = threadIdx.x & 63;
  const float* xr = x + (size_t)row * CDIM;
  float vals[9];
  float sum = 0.f;
#pragma unroll
  for (int i = 0; i < 9; i++) { vals[i] = xr[lane + 64 * i]; sum += vals[i]; }
#pragma unroll
  for (int o = 1; o < 64; o <<= 1) sum += __shfl_xor(sum, o);
  float mu = sum * (1.f / CDIM);
  float vs = 0.f;
#pragma unroll
  for (int i = 0; i < 9; i++) { float d = vals[i] - mu; vs += d * d; }
#pragma unroll
  for (int o = 1; o < 64; o <<= 1) vs += __shfl_xor(vs, o);
  float mult = 1e-5f + rsqrtf(vs * (1.f / CDIM));
  bf16* orow = out + (size_t)row * CDIM;
#pragma unroll
  for (int i = 0; i < 9; i++) {
    int c = lane + 64 * i;
    orow[c] = __float2bfloat16((vals[i] - mu) * mult * g[c] + b[c]);
  }
}

// ---------------- GEMM v5: global_load_lds staging, linear LDS, BMxBN tiles ----------
// out[M,N] = act(A[M,K] @ Bt[N,K]^T + bias) (+ res)
// Waves 2x2; wave tile (BM/2)x(BN/2); per wave MI x NI 16x16 frags, BK=32.
// 128x128: 16 MFMA per barrier-pair per wave (m97 geometry). 128x64: 8.
// LDS tiles LINEAR [rows][32] bf16 (64B rows): ds_read_b128 at row stride 16
// dwords + quad*4 dwords puts exactly 8 dword-accesses on each of the 32
// banks per wave read = the b128 conflict floor. No swizzle needed at BK=32.
// Staging: global_load_lds 16B/lane, LDS dest wave-uniform base + lane*16,
// element order matched to the linear tile. __syncthreads() drains vmcnt(0).
template <int BM, int BN, bool BIAS, bool RES, int ACT, bool OUTBF>
__global__ __launch_bounds__(256) void gemm3(
    const bf16* __restrict__ A, const bf16* __restrict__ Bt,
    const float* __restrict__ bias, const float* __restrict__ res,
    void* __restrict__ outp, int N, int K) {
  constexpr int MI = BM / 32;           // m frags per wave
  constexpr int NI = BN / 32;           // n frags per wave
  constexpr int AJ = BM / 64;           // A gload instrs per wave
  constexpr int BJ = BN / 64;           // B gload instrs per wave
  __shared__ __align__(16) short ldsA[BM * 32];
  __shared__ __align__(16) short ldsB[BN * 32];
  const int tid = threadIdx.x, lane = tid & 63, wave = tid >> 6;
  const int lr = lane & 15, quad = lane >> 4;
  const int m0 = blockIdx.x * BM, n0 = blockIdx.y * BN;
  const int wm = (wave & 1) * (BM / 2), wn = (wave >> 1) * (BN / 2);
  f32x4 acc[MI][NI] = {};

  // staging addressing: instr (wave,j) covers LDS shorts [(wave*J+j)*512, +512)
  // lane l writes 8 shorts at +l*8 -> element row = base16 + l/4, col = (l&3)*8
  const int srow = lane >> 2, scol = (lane & 3) * 8;
  const short* Ag[AJ];
  short* ldsAw[AJ];
#pragma unroll
  for (int j = 0; j < AJ; j++) {
    Ag[j] = (const short*)A + (size_t)(m0 + (wave * AJ + j) * 16 + srow) * K + scol;
    ldsAw[j] = &ldsA[(wave * AJ + j) * 512];
  }
  const short* Bg[BJ];
  short* ldsBw[BJ];
#pragma unroll
  for (int j = 0; j < BJ; j++) {
    Bg[j] = (const short*)Bt + (size_t)(n0 + (wave * BJ + j) * 16 + srow) * K + scol;
    ldsBw[j] = &ldsB[(wave * BJ + j) * 512];
  }

  for (int k0 = 0; k0 < K; k0 += 32) {
#pragma unroll
    for (int j = 0; j < AJ; j++) gload16(Ag[j] + k0, ldsAw[j]);
#pragma unroll
    for (int j = 0; j < BJ; j++) gload16(Bg[j] + k0, ldsBw[j]);
    __syncthreads();
    bf16x8 af[MI], bfv[NI];
#pragma unroll
    for (int mi = 0; mi < MI; mi++)
      af[mi] = *(const bf16x8*)&ldsA[(wm + mi * 16 + lr) * 32 + quad * 8];
#pragma unroll
    for (int ni = 0; ni < NI; ni++)
      bfv[ni] = *(const bf16x8*)&ldsB[(wn + ni * 16 + lr) * 32 + quad * 8];
#pragma unroll
    for (int mi = 0; mi < MI; mi++)
#pragma unroll
      for (int ni = 0; ni < NI; ni++)
        acc[mi][ni] = __builtin_amdgcn_mfma_f32_16x16x32_bf16(af[mi], bfv[ni], acc[mi][ni], 0, 0, 0);
    __syncthreads();
  }

  float* fout = (float*)outp;
  bf16*  bout = (bf16*)outp;
#pragma unroll
  for (int mi = 0; mi < MI; mi++)
#pragma unroll
    for (int ni = 0; ni < NI; ni++) {
      int col = n0 + wn + ni * 16 + lr;
#pragma unroll
      for (int r = 0; r < 4; r++) {
        int row = m0 + wm + mi * 16 + quad * 4 + r;
        float v = acc[mi][ni][r];
        if (BIAS) v += bias[col];
        if (ACT == 1) v = v / (1.f + __expf(-1.702f * v));   // GeLU2
        size_t idx = (size_t)row * N + col;
        if (RES) v += res[idx];
        if (OUTBF) bout[idx] = __float2bfloat16(v);
        else       fout[idx] = v;
      }
    }
}

// ---------------- MFMA flash attention v2 (qkv stride now QKVS) ----------------
__global__ __launch_bounds__(256) void attn_mfma(
    const bf16* __restrict__ qkv, bf16* __restrict__ a) {
  __shared__ short ldsK[12 * 512];     // page (nc*3+c), lane-linear
  __shared__ short ldsVt[80][104];     // [d][key], padded rows
  __shared__ short ldsP[4 * 1024];     // per-wave, fragment-linear (2 kc pages)
  const int bh = blockIdx.y, b = bh >> 3, h = bh & 7;
  const int tid = threadIdx.x, wave = tid >> 6, lane = tid & 63;
  const int lr = lane & 15, quad = lane >> 4;
  const int qt = 15 - (int)blockIdx.x;
  const float scale = 0.11785113019775793f;  // 1/sqrt(72)
  const int qcol = h * DKH, kcol = CDIM + h * DKH, vcol = 2 * CDIM + h * DKH;

  const int qrow = qt * 64 + wave * 16 + lr;
  const short* qg = (const short*)qkv + (size_t)(b * S_LEN + qrow) * QKVS + qcol;
  bf16x8 qfrag[3];
#pragma unroll
  for (int c = 0; c < 3; c++) {
    int d0 = c * 32 + quad * 8;
    bf16x8 z = {0, 0, 0, 0, 0, 0, 0, 0};
    qfrag[c] = (d0 < DKH) ? *(const bf16x8*)(qg + d0) : z;
  }
  f32x4 oacc[5] = {};
  float m[4], l[4];
#pragma unroll
  for (int r = 0; r < 4; r++) { m[r] = -1e30f; l[r] = 0.f; }

  for (int kt = 0; kt <= qt; kt++) {
    __syncthreads();
    {
      const short* kg = (const short*)qkv +
          (size_t)(b * S_LEN + kt * 64 + wave * 16 + lr) * QKVS + kcol + quad * 8;
#pragma unroll
      for (int c = 0; c < 3; c++)
        gload16(kg + c * 32, &ldsK[(wave * 3 + c) * 512]);
    }
    {
      int key = tid & 63, dgb = tid >> 6;
      const short* vg = (const short*)qkv + (size_t)(b * S_LEN + kt * 64 + key) * QKVS + vcol;
#pragma unroll
      for (int pass = 0; pass < 3; pass++) {
        int d0 = (dgb + pass * 4) * 8;  // 0..88
        if (d0 < 80) {
          bf16x8 vv = {0, 0, 0, 0, 0, 0, 0, 0};
          if (d0 < DKH) vv = *(const bf16x8*)(vg + d0);
#pragma unroll
          for (int j = 0; j < 8; j++) ldsVt[d0 + j][key] = vv[j];
        }
      }
    }
    __syncthreads();
    f32x4 sacc[4] = {};
#pragma unroll
    for (int nc = 0; nc < 4; nc++)
#pragma unroll
      for (int c = 0; c < 3; c++) {
        bf16x8 kf = *(const bf16x8*)&ldsK[(nc * 3 + c) * 512 + lane * 8];
        sacc[nc] = __builtin_amdgcn_mfma_f32_16x16x32_bf16(qfrag[c], kf, sacc[nc], 0, 0, 0);
      }
    float tmax[4];
#pragma unroll
    for (int r = 0; r < 4; r++) tmax[r] = -1e30f;
    bool diag = (kt == qt);
#pragma unroll
    for (int nc = 0; nc < 4; nc++)
#pragma unroll
      for (int r = 0; r < 4; r++) {
        float s = sacc[nc][r] * scale;
        if (diag && (nc * 16 + lr > wave * 16 + quad * 4 + r)) s = -1e30f;
        sacc[nc][r] = s;
        tmax[r] = fmaxf(tmax[r], s);
      }
#pragma unroll
    for (int r = 0; r < 4; r++) {
      tmax[r] = fmaxf(tmax[r], __shfl_xor(tmax[r], 1));
      tmax[r] = fmaxf(tmax[r], __shfl_xor(tmax[r], 2));
      tmax[r] = fmaxf(tmax[r], __shfl_xor(tmax[r], 4));
      tmax[r] = fmaxf(tmax[r], __shfl_xor(tmax[r], 8));
    }
    float alpha[4], psum[4];
#pragma unroll
    for (int r = 0; r < 4; r++) {
      float mn = fmaxf(m[r], tmax[r]);
      alpha[r] = __expf(m[r] - mn);
      m[r] = mn;
      psum[r] = 0.f;
    }
#pragma unroll
    for (int nc = 0; nc < 4; nc++)
#pragma unroll
      for (int r = 0; r < 4; r++) {
        float p = __expf(sacc[nc][r] - m[r]);
        psum[r] += p;
        int col = nc * 16 + lr;
        ldsP[wave * 1024 + (col >> 5) * 512 +
             (((col >> 3) & 3) * 16 + quad * 4 + r) * 8 + (col & 7)] = f2bf_bits(p);
      }
#pragma unroll
    for (int r = 0; r < 4; r++) {
      psum[r] += __shfl_xor(psum[r], 1);
      psum[r] += __shfl_xor(psum[r], 2);
      psum[r] += __shfl_xor(psum[r], 4);
      psum[r] += __shfl_xor(psum[r], 8);
      l[r] = l[r] * alpha[r] + psum[r];
    }
#pragma unroll
    for (int dc = 0; dc < 5; dc++)
#pragma unroll
      for (int r = 0; r < 4; r++) oacc[dc][r] *= alpha[r];
    __builtin_amdgcn_sched_barrier(0);
    bf16x8 pfrag[2];
#pragma unroll
    for (int kc = 0; kc < 2; kc++)
      pfrag[kc] = *(const bf16x8*)&ldsP[wave * 1024 + kc * 512 + lane * 8];
#pragma unroll
    for (int dc = 0; dc < 5; dc++)
#pragma unroll
      for (int kc = 0; kc < 2; kc++) {
        bf16x8 vf = *(const bf16x8*)&ldsVt[dc * 16 + lr][kc * 32 + quad * 8];
        oacc[dc] = __builtin_amdgcn_mfma_f32_16x16x32_bf16(pfrag[kc], vf, oacc[dc], 0, 0, 0);
      }
  }  // kt

#pragma unroll
  for (int dc = 0; dc < 5; dc++) {
    int d = dc * 16 + lr;
    if (d < DKH) {
#pragma unroll
      for (int r = 0; r < 4; r++) {
        int row = qt * 64 + wave * 16 + quad * 4 + r;
        float val = oacc[dc][r] / l[r];
        a[(size_t)(b * S_LEN + row) * CDIM + h * DKH + d] = __float2bfloat16(val);
      }
    }
  }
}

// ---------------- launch ----------------
extern "C" void kernel_launch(void* const* d_in, const int* in_sizes, int n_in,
                              void* d_out, int out_size, void* d_ws, size_t ws_size,
                              hipStream_t stream) {
  const float* x    = (const float*)d_in[0];
  const float* pos0 = (const float*)d_in[1];
  const float* pos1 = (const float*)d_in[2];
  const float* pos2 = (const float*)d_in[3];
  const float* ln1g = (const float*)d_in[4];
  const float* ln1b = (const float*)d_in[5];
  const float* wq   = (const float*)d_in[6];
  const float* wk   = (const float*)d_in[7];
  const float* wv   = (const float*)d_in[8];
  const float* wo   = (const float*)d_in[9];
  const float* wob  = (const float*)d_in[10];
  const float* ln2g = (const float*)d_in[11];
  const float* ln2b = (const float*)d_in[12];
  const float* w1   = (const float*)d_in[13];
  const float* b1   = (const float*)d_in[14];
  const float* w2   = (const float*)d_in[15];
  const float* b2   = (const float*)d_in[16];

  char* ws = (char*)d_ws;
  size_t off = 0;
  auto alloc = [&](size_t bytes) {
    char* p = ws + off;
    off += (bytes + 255) & ~(size_t)255;
    return p;
  };
  bf16* wqkvT = (bf16*)alloc((size_t)4 * QKVS * CDIM * sizeof(bf16));  // N padded
  bf16* woT   = (bf16*)alloc((size_t)4 * CDIM * CDIM * sizeof(bf16));
  bf16* w1T   = (bf16*)alloc((size_t)4 * FFDIM * CDIM * sizeof(bf16));
  bf16* w2T   = (bf16*)alloc((size_t)4 * CDIM * FFDIM * sizeof(bf16));
  bf16* hbuf  = (bf16*)alloc((size_t)MROWS * CDIM * sizeof(bf16));
  bf16* abuf  = (bf16*)alloc((size_t)MROWS * CDIM * sizeof(bf16));
  bf16* ubuf  = (bf16*)alloc((size_t)MROWS * FFDIM * sizeof(bf16));
  bf16* qkvb  = (bf16*)alloc((size_t)MROWS * QKVS * sizeof(bf16));     // stride padded
  float* xf   = (float*)d_out;   // residual stream lives in d_out (fp32)

  const size_t ils  = (size_t)CDIM * CDIM;
  const size_t ils2 = (size_t)CDIM * FFDIM;
  const size_t qkv_ls = (size_t)QKVS * CDIM;   // padded per-layer stride
  transpose_cvt<<<dim3(18, 18, 4), 256, 0, stream>>>(wq, wqkvT, CDIM, CDIM, ils, qkv_ls);
  transpose_cvt<<<dim3(18, 18, 4), 256, 0, stream>>>(wk, wqkvT + (size_t)CDIM * CDIM, CDIM, CDIM, ils, qkv_ls);
  transpose_cvt<<<dim3(18, 18, 4), 256, 0, stream>>>(wv, wqkvT + (size_t)2 * CDIM * CDIM, CDIM, CDIM, ils, qkv_ls);
  transpose_cvt<<<dim3(18, 18, 4), 256, 0, stream>>>(wo, woT, CDIM, CDIM, ils, ils);
  transpose_cvt<<<dim3(72, 18, 4), 256, 0, stream>>>(w1, w1T, CDIM, FFDIM, ils2, ils2);
  transpose_cvt<<<dim3(18, 72, 4), 256, 0, stream>>>(w2, w2T, FFDIM, CDIM, ils2, ils2);

  build_xf<<<2304, 256, 0, stream>>>(x, pos0, pos1, pos2, xf);

  for (int l = 0; l < 4; l++) {
    bf16* wqkv_l = wqkvT + (size_t)l * qkv_ls;
    bf16* wo_l   = woT   + (size_t)l * ils;
    bf16* w1_l   = w1T   + (size_t)l * ils2;
    bf16* w2_l   = w2T   + (size_t)l * ils2;

    ln_kernel<<<1024, 256, 0, stream>>>(xf, ln1g + l * CDIM, ln1b + l * CDIM, hbuf);
    // fused QKV: [4096,576] x [1792,576]^T -> qkvb (128x128, 448 blocks)
    gemm3<128, 128, false, false, 0, true><<<dim3(32, QKVS / 128), 256, 0, stream>>>(
        hbuf, wqkv_l, nullptr, nullptr, qkvb, QKVS, CDIM);
    attn_mfma<<<dim3(16, 32), 256, 0, stream>>>(qkvb, abuf);
    // proj + bias + residual -> xf (128x64, 288 blocks)
    gemm3<128, 64, true, true, 0, false><<<dim3(32, CDIM / 64), 256, 0, stream>>>(
        abuf, wo_l, wob + l * CDIM, xf, xf, CDIM, CDIM);
    ln_kernel<<<1024, 256, 0, stream>>>(xf, ln2g + l * CDIM, ln2b + l * CDIM, hbuf);
    // FFN1 + bias + GeLU2 -> ubuf (128x128, 576 blocks)
    gemm3<128, 128, true, false, 1, true><<<dim3(32, FFDIM / 128), 256, 0, stream>>>(
        hbuf, w1_l, b1 + l * FFDIM, nullptr, ubuf, FFDIM, CDIM);
    // FFN2 + bias + residual -> xf (128x64, 288 blocks)
    gemm3<128, 64, true, true, 0, false><<<dim3(32, CDIM / 64), 256, 0, stream>>>(
        ubuf, w2_l, b2 + l * CDIM, xf, xf, CDIM, FFDIM);
  }
}

// Round 3
// 719.449 us; speedup vs baseline: 1.1337x; 1.1337x over previous
//
#include <hip/hip_runtime.h>
#include <hip/hip_bf16.h>

typedef __hip_bfloat16 bf16;
using bf16x8 = __attribute__((ext_vector_type(8))) short;
using f32x4  = __attribute__((ext_vector_type(4))) float;

#define S_LEN 1024
#define CDIM  576
#define NHEAD 8
#define DKH   72
#define BATCH 4
#define MROWS 4096   // B*S
#define FFDIM 2304
#define QKVN  1728   // 3*C

// async global->LDS, 16B per lane, lane-ordered LDS destination
__device__ __forceinline__ void gload16(const void* g, void* l) {
  __builtin_amdgcn_global_load_lds(
      (const __attribute__((address_space(1))) unsigned int*)g,
      (__attribute__((address_space(3))) unsigned int*)l, 16, 0, 0);
}

// float -> bf16 bits (RNE), pure integer math (type-safe for LDS punning)
__device__ __forceinline__ short f2bf_bits(float x) {
  unsigned int u = __float_as_uint(x);
  u += 0x7fffu + ((u >> 16) & 1u);
  return (short)(u >> 16);
}

// ---------------- weight transpose + fp32->bf16 convert ----------------
__global__ __launch_bounds__(256) void transpose_cvt(
    const float* __restrict__ in, bf16* __restrict__ out, int K, int N,
    size_t in_ls, size_t out_ls) {
  __shared__ float tile[32][33];
  const float* inl = in + (size_t)blockIdx.z * in_ls;
  bf16* outl = out + (size_t)blockIdx.z * out_ls;
  int n0 = blockIdx.x * 32, k0 = blockIdx.y * 32;
  int tx = threadIdx.x & 31, ty = threadIdx.x >> 5;   // ty 0..7
#pragma unroll
  for (int i = 0; i < 32; i += 8)
    tile[ty + i][tx] = inl[(size_t)(k0 + ty + i) * N + (n0 + tx)];
  __syncthreads();
#pragma unroll
  for (int i = 0; i < 32; i += 8)
    outl[(size_t)(n0 + ty + i) * K + (k0 + tx)] = __float2bfloat16(tile[tx][ty + i]);
}

// ---------------- xf = right_shift(x) + pos ----------------
__global__ __launch_bounds__(256) void build_xf(
    const float* __restrict__ x, const float* __restrict__ p0,
    const float* __restrict__ p1, const float* __restrict__ p2,
    float* __restrict__ xf) {
  int idx = blockIdx.x * 256 + threadIdx.x;      // one float4 per thread
  int c4 = idx % 144;
  int s  = (idx / 144) & (S_LEN - 1);
  int b  = idx / (144 * S_LEN);
  int c  = c4 * 4;
  int t = s >> 8, hh = (s >> 4) & 15, w = s & 15;
  float4 pv;
  if (c < 192)       pv = *(const float4*)&p0[t  * 192 + c];
  else if (c < 384)  pv = *(const float4*)&p1[hh * 192 + c - 192];
  else               pv = *(const float4*)&p2[w  * 192 + c - 384];
  float4 xv = make_float4(0.f, 0.f, 0.f, 0.f);
  if (s > 0) xv = *(const float4*)&x[((size_t)b * S_LEN + s - 1) * CDIM + c];
  float4 r = make_float4(xv.x + pv.x, xv.y + pv.y, xv.z + pv.z, xv.w + pv.w);
  *(float4*)&xf[((size_t)b * S_LEN + s) * CDIM + c] = r;
}

// ---------------- LayerNorm (eps added to rsqrt, per reference) ----------------
__global__ __launch_bounds__(256) void ln_kernel(
    const float* __restrict__ x, const float* __restrict__ g,
    const float* __restrict__ b, bf16* __restrict__ out) {
  int row  = blockIdx.x * 4 + (threadIdx.x >> 6);
  int lane = threadIdx.x & 63;
  const float* xr = x + (size_t)row * CDIM;
  float vals[9];
  float sum = 0.f;
#pragma unroll
  for (int i = 0; i < 9; i++) { vals[i] = xr[lane + 64 * i]; sum += vals[i]; }
#pragma unroll
  for (int o = 1; o < 64; o <<= 1) sum += __shfl_xor(sum, o);
  float mu = sum * (1.f / CDIM);
  float vs = 0.f;
#pragma unroll
  for (int i = 0; i < 9; i++) { float d = vals[i] - mu; vs += d * d; }
#pragma unroll
  for (int o = 1; o < 64; o <<= 1) vs += __shfl_xor(vs, o);
  float mult = 1e-5f + rsqrtf(vs * (1.f / CDIM));
  bf16* orow = out + (size_t)row * CDIM;
#pragma unroll
  for (int i = 0; i < 9; i++) {
    int c = lane + 64 * i;
    orow[c] = __float2bfloat16((vals[i] - mu) * mult * g[c] + b[c]);
  }
}

// ---------------- GEMM (round-1 geometry: the 739us-verified config) ----------
// out[M,N] = act(A[M,K] @ Bt[N,K]^T + bias) (+ res)
// LDS LINEAR [rows][32] bf16 (64B rows): ds_read_b128 conflict floor, no swizzle.
// Staging via global_load_lds 16B/lane; __syncthreads() drains vmcnt(0).
template <int BM, int BN, bool BIAS, bool RES, int ACT, bool OUTBF>
__global__ __launch_bounds__(256) void gemm3(
    const bf16* __restrict__ A, const bf16* __restrict__ Bt,
    const float* __restrict__ bias, const float* __restrict__ res,
    void* __restrict__ outp, int N, int K) {
  constexpr int MI = BM / 32;           // m frags per wave
  constexpr int NI = BN / 32;           // n frags per wave
  constexpr int AJ = BM / 64;           // A gload instrs per wave
  constexpr int BJ = BN / 64;           // B gload instrs per wave
  __shared__ __align__(16) short ldsA[BM * 32];
  __shared__ __align__(16) short ldsB[BN * 32];
  const int tid = threadIdx.x, lane = tid & 63, wave = tid >> 6;
  const int lr = lane & 15, quad = lane >> 4;
  const int m0 = blockIdx.x * BM, n0 = blockIdx.y * BN;
  const int wm = (wave & 1) * (BM / 2), wn = (wave >> 1) * (BN / 2);
  f32x4 acc[MI][NI] = {};

  const int srow = lane >> 2, scol = (lane & 3) * 8;
  const short* Ag[AJ];
  short* ldsAw[AJ];
#pragma unroll
  for (int j = 0; j < AJ; j++) {
    Ag[j] = (const short*)A + (size_t)(m0 + (wave * AJ + j) * 16 + srow) * K + scol;
    ldsAw[j] = &ldsA[(wave * AJ + j) * 512];
  }
  const short* Bg[BJ];
  short* ldsBw[BJ];
#pragma unroll
  for (int j = 0; j < BJ; j++) {
    Bg[j] = (const short*)Bt + (size_t)(n0 + (wave * BJ + j) * 16 + srow) * K + scol;
    ldsBw[j] = &ldsB[(wave * BJ + j) * 512];
  }

  for (int k0 = 0; k0 < K; k0 += 32) {
#pragma unroll
    for (int j = 0; j < AJ; j++) gload16(Ag[j] + k0, ldsAw[j]);
#pragma unroll
    for (int j = 0; j < BJ; j++) gload16(Bg[j] + k0, ldsBw[j]);
    __syncthreads();
    bf16x8 af[MI], bfv[NI];
#pragma unroll
    for (int mi = 0; mi < MI; mi++)
      af[mi] = *(const bf16x8*)&ldsA[(wm + mi * 16 + lr) * 32 + quad * 8];
#pragma unroll
    for (int ni = 0; ni < NI; ni++)
      bfv[ni] = *(const bf16x8*)&ldsB[(wn + ni * 16 + lr) * 32 + quad * 8];
#pragma unroll
    for (int mi = 0; mi < MI; mi++)
#pragma unroll
      for (int ni = 0; ni < NI; ni++)
        acc[mi][ni] = __builtin_amdgcn_mfma_f32_16x16x32_bf16(af[mi], bfv[ni], acc[mi][ni], 0, 0, 0);
    __syncthreads();
  }

  float* fout = (float*)outp;
  bf16*  bout = (bf16*)outp;
#pragma unroll
  for (int mi = 0; mi < MI; mi++)
#pragma unroll
    for (int ni = 0; ni < NI; ni++) {
      int col = n0 + wn + ni * 16 + lr;
#pragma unroll
      for (int r = 0; r < 4; r++) {
        int row = m0 + wm + mi * 16 + quad * 4 + r;
        float v = acc[mi][ni][r];
        if (BIAS) v += bias[col];
        if (ACT == 1) v = v / (1.f + __expf(-1.702f * v));   // GeLU2
        size_t idx = (size_t)row * N + col;
        if (RES) v += res[idx];
        if (OUTBF) bout[idx] = __float2bfloat16(v);
        else       fout[idx] = v;
      }
    }
}

// ---------------- MFMA flash attention v3: double-buffered K/V prefetch -------
// Per kt iteration (ONE barrier, was two):
//   issue K gloads(kt+1)->ldsK[nxt]; issue V global loads(kt+1)->regs
//   QK MFMA(ldsK[cur]) ; softmax ; PV MFMA(ldsVt[cur])
//   ds_write V regs->ldsVt[nxt]   (vmcnt wait covered by ~full iter of compute)
//   __syncthreads()               (drains vmcnt: K gloads; lgkm: V writes)
// K staging shrunk 12->9 pages: chunk2 keeps only cols 64..71 (qfrag==0 beyond
// d=72, so kf values for quad>=1 are don't-cares and read the quad0 data).
__global__ __launch_bounds__(256) void attn_mfma(
    const bf16* __restrict__ qkv, bf16* __restrict__ a) {
  __shared__ __align__(16) short ldsK[2][9 * 512];   // pages: w*2+c (c=0,1), 8=col64 page
  __shared__ __align__(16) short ldsVt[2][80][104];  // [d][key], padded rows
  __shared__ __align__(16) short ldsP[4 * 1024];     // per-wave, fragment-linear
  const int bh = blockIdx.y, b = bh >> 3, h = bh & 7;
  const int tid = threadIdx.x, wave = tid >> 6, lane = tid & 63;
  const int lr = lane & 15, quad = lane >> 4;
  const int qt = 15 - (int)blockIdx.x;
  const float scale = 0.11785113019775793f;  // 1/sqrt(72)
  const int qcol = h * DKH, kcol = CDIM + h * DKH, vcol = 2 * CDIM + h * DKH;

  const int qrow = qt * 64 + wave * 16 + lr;
  const short* qg = (const short*)qkv + (size_t)(b * S_LEN + qrow) * QKVN + qcol;
  bf16x8 qfrag[3];
#pragma unroll
  for (int c = 0; c < 3; c++) {
    int d0 = c * 32 + quad * 8;
    bf16x8 z = {0, 0, 0, 0, 0, 0, 0, 0};
    qfrag[c] = (d0 < DKH) ? *(const bf16x8*)(qg + d0) : z;
  }
  f32x4 oacc[5] = {};
  float m[4], l[4];
#pragma unroll
  for (int r = 0; r < 4; r++) { m[r] = -1e30f; l[r] = 0.f; }

  // staging bases (advance by kt*64*QKVN)
  const size_t ktstep = (size_t)64 * QKVN;
  const short* kg0 = (const short*)qkv + (size_t)(b * S_LEN + wave * 16 + lr) * QKVN + kcol + quad * 8;
  const short* kg2 = (const short*)qkv + (size_t)(b * S_LEN + lane) * QKVN + kcol + 64;  // wave0 page-8
  const int vkey = tid & 63, vdgb = tid >> 6;
  const short* vg0 = (const short*)qkv + (size_t)(b * S_LEN + vkey) * QKVN + vcol;

  // ---- prologue: stage kt=0 into buf 0 ----
  {
#pragma unroll
    for (int c = 0; c < 2; c++)
      gload16(kg0 + c * 32, &ldsK[0][(wave * 2 + c) * 512]);
    if (wave == 0) gload16(kg2, &ldsK[0][8 * 512]);
#pragma unroll
    for (int pass = 0; pass < 3; pass++) {
      int d0 = (vdgb + pass * 4) * 8;  // 0..88
      if (d0 < 80) {
        bf16x8 vv = {0, 0, 0, 0, 0, 0, 0, 0};
        if (d0 < DKH) vv = *(const bf16x8*)(vg0 + d0);
#pragma unroll
        for (int j = 0; j < 8; j++) ldsVt[0][d0 + j][vkey] = vv[j];
      }
    }
  }
  __syncthreads();

  for (int kt = 0; kt <= qt; kt++) {
    const int cur = kt & 1, nxt = cur ^ 1;
    const bool pf = (kt < qt);
    bf16x8 vpre[3];
    if (pf) {
      const short* kg = kg0 + (size_t)(kt + 1) * ktstep;
#pragma unroll
      for (int c = 0; c < 2; c++)
        gload16(kg + c * 32, &ldsK[nxt][(wave * 2 + c) * 512]);
      if (wave == 0) gload16(kg2 + (size_t)(kt + 1) * ktstep, &ldsK[nxt][8 * 512]);
      const short* vg = vg0 + (size_t)(kt + 1) * ktstep;
#pragma unroll
      for (int pass = 0; pass < 3; pass++) {
        int d0 = (vdgb + pass * 4) * 8;
        bf16x8 z = {0, 0, 0, 0, 0, 0, 0, 0};
        vpre[pass] = (d0 < DKH) ? *(const bf16x8*)(vg + d0) : z;
      }
    }
    // ---- QK^T ----
    f32x4 sacc[4] = {};
#pragma unroll
    for (int nc = 0; nc < 4; nc++) {
      bf16x8 kf0 = *(const bf16x8*)&ldsK[cur][(nc * 2 + 0) * 512 + lane * 8];
      sacc[nc] = __builtin_amdgcn_mfma_f32_16x16x32_bf16(qfrag[0], kf0, sacc[nc], 0, 0, 0);
      bf16x8 kf1 = *(const bf16x8*)&ldsK[cur][(nc * 2 + 1) * 512 + lane * 8];
      sacc[nc] = __builtin_amdgcn_mfma_f32_16x16x32_bf16(qfrag[1], kf1, sacc[nc], 0, 0, 0);
      bf16x8 kf2 = *(const bf16x8*)&ldsK[cur][8 * 512 + (nc * 16 + lr) * 8];
      sacc[nc] = __builtin_amdgcn_mfma_f32_16x16x32_bf16(qfrag[2], kf2, sacc[nc], 0, 0, 0);
    }
    // ---- online softmax ----
    float tmax[4];
#pragma unroll
    for (int r = 0; r < 4; r++) tmax[r] = -1e30f;
    bool diag = (kt == qt);
#pragma unroll
    for (int nc = 0; nc < 4; nc++)
#pragma unroll
      for (int r = 0; r < 4; r++) {
        float s = sacc[nc][r] * scale;
        if (diag && (nc * 16 + lr > wave * 16 + quad * 4 + r)) s = -1e30f;
        sacc[nc][r] = s;
        tmax[r] = fmaxf(tmax[r], s);
      }
#pragma unroll
    for (int r = 0; r < 4; r++) {
      tmax[r] = fmaxf(tmax[r], __shfl_xor(tmax[r], 1));
      tmax[r] = fmaxf(tmax[r], __shfl_xor(tmax[r], 2));
      tmax[r] = fmaxf(tmax[r], __shfl_xor(tmax[r], 4));
      tmax[r] = fmaxf(tmax[r], __shfl_xor(tmax[r], 8));
    }
    float alpha[4], psum[4];
#pragma unroll
    for (int r = 0; r < 4; r++) {
      float mn = fmaxf(m[r], tmax[r]);
      alpha[r] = __expf(m[r] - mn);
      m[r] = mn;
      psum[r] = 0.f;
    }
#pragma unroll
    for (int nc = 0; nc < 4; nc++)
#pragma unroll
      for (int r = 0; r < 4; r++) {
        float p = __expf(sacc[nc][r] - m[r]);
        psum[r] += p;
        int col = nc * 16 + lr;
        ldsP[wave * 1024 + (col >> 5) * 512 +
             (((col >> 3) & 3) * 16 + quad * 4 + r) * 8 + (col & 7)] = f2bf_bits(p);
      }
#pragma unroll
    for (int r = 0; r < 4; r++) {
      psum[r] += __shfl_xor(psum[r], 1);
      psum[r] += __shfl_xor(psum[r], 2);
      psum[r] += __shfl_xor(psum[r], 4);
      psum[r] += __shfl_xor(psum[r], 8);
      l[r] = l[r] * alpha[r] + psum[r];
    }
#pragma unroll
    for (int dc = 0; dc < 5; dc++)
#pragma unroll
      for (int r = 0; r < 4; r++) oacc[dc][r] *= alpha[r];
    __builtin_amdgcn_sched_barrier(0);
    // ---- PV ----
    bf16x8 pfrag[2];
#pragma unroll
    for (int kc = 0; kc < 2; kc++)
      pfrag[kc] = *(const bf16x8*)&ldsP[wave * 1024 + kc * 512 + lane * 8];
#pragma unroll
    for (int dc = 0; dc < 5; dc++)
#pragma unroll
      for (int kc = 0; kc < 2; kc++) {
        bf16x8 vf = *(const bf16x8*)&ldsVt[cur][dc * 16 + lr][kc * 32 + quad * 8];
        oacc[dc] = __builtin_amdgcn_mfma_f32_16x16x32_bf16(pfrag[kc], vf, oacc[dc], 0, 0, 0);
      }
    // ---- late V write (prefetched regs -> ldsVt[nxt]) ----
    if (pf) {
#pragma unroll
      for (int pass = 0; pass < 3; pass++) {
        int d0 = (vdgb + pass * 4) * 8;
        if (d0 < 80) {
#pragma unroll
          for (int j = 0; j < 8; j++) ldsVt[nxt][d0 + j][vkey] = vpre[pass][j];
        }
      }
    }
    __syncthreads();
  }  // kt

#pragma unroll
  for (int dc = 0; dc < 5; dc++) {
    int d = dc * 16 + lr;
    if (d < DKH) {
#pragma unroll
      for (int r = 0; r < 4; r++) {
        int row = qt * 64 + wave * 16 + quad * 4 + r;
        float val = oacc[dc][r] / l[r];
        a[(size_t)(b * S_LEN + row) * CDIM + h * DKH + d] = __float2bfloat16(val);
      }
    }
  }
}

// ---------------- launch ----------------
extern "C" void kernel_launch(void* const* d_in, const int* in_sizes, int n_in,
                              void* d_out, int out_size, void* d_ws, size_t ws_size,
                              hipStream_t stream) {
  const float* x    = (const float*)d_in[0];
  const float* pos0 = (const float*)d_in[1];
  const float* pos1 = (const float*)d_in[2];
  const float* pos2 = (const float*)d_in[3];
  const float* ln1g = (const float*)d_in[4];
  const float* ln1b = (const float*)d_in[5];
  const float* wq   = (const float*)d_in[6];
  const float* wk   = (const float*)d_in[7];
  const float* wv   = (const float*)d_in[8];
  const float* wo   = (const float*)d_in[9];
  const float* wob  = (const float*)d_in[10];
  const float* ln2g = (const float*)d_in[11];
  const float* ln2b = (const float*)d_in[12];
  const float* w1   = (const float*)d_in[13];
  const float* b1   = (const float*)d_in[14];
  const float* w2   = (const float*)d_in[15];
  const float* b2   = (const float*)d_in[16];

  char* ws = (char*)d_ws;
  size_t off = 0;
  auto alloc = [&](size_t bytes) {
    char* p = ws + off;
    off += (bytes + 255) & ~(size_t)255;
    return p;
  };
  bf16* wqkvT = (bf16*)alloc((size_t)4 * QKVN * CDIM * sizeof(bf16));
  bf16* woT   = (bf16*)alloc((size_t)4 * CDIM * CDIM * sizeof(bf16));
  bf16* w1T   = (bf16*)alloc((size_t)4 * FFDIM * CDIM * sizeof(bf16));
  bf16* w2T   = (bf16*)alloc((size_t)4 * CDIM * FFDIM * sizeof(bf16));
  bf16* hbuf  = (bf16*)alloc((size_t)MROWS * CDIM * sizeof(bf16));
  bf16* abuf  = (bf16*)alloc((size_t)MROWS * CDIM * sizeof(bf16));
  bf16* ubuf  = (bf16*)alloc((size_t)MROWS * FFDIM * sizeof(bf16));
  bf16* qkvb  = (bf16*)alloc((size_t)MROWS * QKVN * sizeof(bf16));
  float* xf   = (float*)d_out;   // residual stream lives in d_out (fp32)

  const size_t ils  = (size_t)CDIM * CDIM;
  const size_t ils2 = (size_t)CDIM * FFDIM;
  const size_t qkv_ls = (size_t)QKVN * CDIM;
  transpose_cvt<<<dim3(18, 18, 4), 256, 0, stream>>>(wq, wqkvT, CDIM, CDIM, ils, qkv_ls);
  transpose_cvt<<<dim3(18, 18, 4), 256, 0, stream>>>(wk, wqkvT + (size_t)CDIM * CDIM, CDIM, CDIM, ils, qkv_ls);
  transpose_cvt<<<dim3(18, 18, 4), 256, 0, stream>>>(wv, wqkvT + (size_t)2 * CDIM * CDIM, CDIM, CDIM, ils, qkv_ls);
  transpose_cvt<<<dim3(18, 18, 4), 256, 0, stream>>>(wo, woT, CDIM, CDIM, ils, ils);
  transpose_cvt<<<dim3(72, 18, 4), 256, 0, stream>>>(w1, w1T, CDIM, FFDIM, ils2, ils2);
  transpose_cvt<<<dim3(18, 72, 4), 256, 0, stream>>>(w2, w2T, FFDIM, CDIM, ils2, ils2);

  build_xf<<<2304, 256, 0, stream>>>(x, pos0, pos1, pos2, xf);

  for (int l = 0; l < 4; l++) {
    bf16* wqkv_l = wqkvT + (size_t)l * qkv_ls;
    bf16* wo_l   = woT   + (size_t)l * ils;
    bf16* w1_l   = w1T   + (size_t)l * ils2;
    bf16* w2_l   = w2T   + (size_t)l * ils2;

    ln_kernel<<<1024, 256, 0, stream>>>(xf, ln1g + l * CDIM, ln1b + l * CDIM, hbuf);
    // fused QKV: [4096,576] x [1728,576]^T -> qkvb (128x64, 864 blocks)
    gemm3<128, 64, false, false, 0, true><<<dim3(32, QKVN / 64), 256, 0, stream>>>(
        hbuf, wqkv_l, nullptr, nullptr, qkvb, QKVN, CDIM);
    attn_mfma<<<dim3(16, 32), 256, 0, stream>>>(qkvb, abuf);
    // proj + bias + residual -> xf (64x64, 576 blocks)
    gemm3<64, 64, true, true, 0, false><<<dim3(64, CDIM / 64), 256, 0, stream>>>(
        abuf, wo_l, wob + l * CDIM, xf, xf, CDIM, CDIM);
    ln_kernel<<<1024, 256, 0, stream>>>(xf, ln2g + l * CDIM, ln2b + l * CDIM, hbuf);
    // FFN1 + bias + GeLU2 -> ubuf (128x64, 1152 blocks)
    gemm3<128, 64, true, false, 1, true><<<dim3(32, FFDIM / 64), 256, 0, stream>>>(
        hbuf, w1_l, b1 + l * FFDIM, nullptr, ubuf, FFDIM, CDIM);
    // FFN2 + bias + residual -> xf (64x64, 576 blocks)
    gemm3<64, 64, true, true, 0, false><<<dim3(64, CDIM / 64), 256, 0, stream>>>(
        ubuf, w2_l, b2 + l * CDIM, xf, xf, CDIM, FFDIM);
  }
}